// Round 5
// baseline (641.675 us; speedup 1.0000x reference)
//
#include <hip/hip_runtime.h>

// Level-phased multiresolution hash-grid embedding, round 5.
// Round-4 model: kernel time ≈ lane-memory-ops × 1.15 cyc / 256 CU.
// A was 12 lane-ops/point·level (3 x-reload + 8 gathers + 1 store).
// This round: (P) pack (x+1) into float4 once -> x costs 1 lane-op/point·level;
// (B') transpose handles 2 points/thread via f32x4 ws loads (24 -> 12 lane-ops/pt).

#define TSIZE (1u << 19)
#define HMASK (TSIZE - 1u)
#define P1 2654435761u
#define P2 805459861u

typedef float f32x4 __attribute__((ext_vector_type(4)));
typedef float f32x2 __attribute__((ext_vector_type(2)));

__constant__ float RES_C[16] = {16.f, 20.f, 25.f, 32.f, 40.f, 50.f, 64.f, 80.f,
                                101.f, 128.f, 161.f, 203.f, 256.f, 322.f, 406.f, 512.f};

// ---------------- Prepass: pack (x+1) into float4 ----------------
__global__ __launch_bounds__(256) void pack_x_kernel(
    const float* __restrict__ x, f32x4* __restrict__ xp, int npoints)
{
    const int p = blockIdx.x * 256 + threadIdx.x;
    if (p >= npoints) return;
    f32x4 v = { x[3 * p + 0] + 1.0f, x[3 * p + 1] + 1.0f, x[3 * p + 2] + 1.0f, 0.0f };
    xp[p] = v;
}

// ---------------- Kernel A: one level per block, packed-x variant ----------------
__global__ __launch_bounds__(256) void gather_level_packed(
    const f32x4* __restrict__ xp,
    const float* __restrict__ tables,
    f32x2* __restrict__ ws,          // [16][npoints] float2
    int npoints, int levelShift)
{
    const int level = blockIdx.x >> levelShift;              // slow index -> phases
    const int chunk = blockIdx.x & ((1 << levelShift) - 1);
    const float halfr = 0.5f * RES_C[level];                 // 1/grid, exact

    const float2* __restrict__ tab = (const float2*)tables + (size_t)level * TSIZE;
    f32x2* __restrict__ wrow = ws + (size_t)level * npoints;

#pragma unroll
    for (int q = 0; q < 2; ++q) {
        const int p = chunk * 512 + q * 256 + threadIdx.x;
        if (p >= npoints) break;

        const f32x4 P4 = xp[p];                              // 1 lane-op
        const float fx = P4.x * halfr;
        const float fy = P4.y * halfr;
        const float fz = P4.z * halfr;

        const float bx = floorf(fx), by = floorf(fy), bz = floorf(fz);
        const float wx = fx - bx, wy = fy - by, wz = fz - bz;

        const unsigned ix0 = (unsigned)(int)bx;              // * prime 1
        const unsigned iy0 = (unsigned)(int)by * P1;
        const unsigned iz0 = (unsigned)(int)bz * P2;
        const unsigned ix1 = ix0 + 1u, iy1 = iy0 + P1, iz1 = iz0 + P2;

        const float2 v000 = tab[(ix0 ^ iy0 ^ iz0) & HMASK];
        const float2 v001 = tab[(ix0 ^ iy0 ^ iz1) & HMASK];
        const float2 v010 = tab[(ix0 ^ iy1 ^ iz0) & HMASK];
        const float2 v011 = tab[(ix0 ^ iy1 ^ iz1) & HMASK];
        const float2 v100 = tab[(ix1 ^ iy0 ^ iz0) & HMASK];
        const float2 v101 = tab[(ix1 ^ iy0 ^ iz1) & HMASK];
        const float2 v110 = tab[(ix1 ^ iy1 ^ iz0) & HMASK];
        const float2 v111 = tab[(ix1 ^ iy1 ^ iz1) & HMASK];

        const float c00a = v000.x + wx * (v100.x - v000.x);
        const float c00b = v000.y + wx * (v100.y - v000.y);
        const float c01a = v001.x + wx * (v101.x - v001.x);
        const float c01b = v001.y + wx * (v101.y - v001.y);
        const float c10a = v010.x + wx * (v110.x - v010.x);
        const float c10b = v010.y + wx * (v110.y - v010.y);
        const float c11a = v011.x + wx * (v111.x - v011.x);
        const float c11b = v011.y + wx * (v111.y - v011.y);

        const float c0a = c00a + wy * (c10a - c00a);
        const float c0b = c00b + wy * (c10b - c00b);
        const float c1a = c01a + wy * (c11a - c01a);
        const float c1b = c01b + wy * (c11b - c01b);

        f32x2 r = { c0a + wz * (c1a - c0a), c0b + wz * (c1b - c0b) };
        __builtin_nontemporal_store(r, wrow + p);            // full 64 B lines
    }
}

// ---------------- Kernel A fallback: raw-x variant (round 4) ----------------
__global__ __launch_bounds__(256) void gather_level_kernel(
    const float* __restrict__ x,
    const float* __restrict__ tables,
    f32x2* __restrict__ ws,
    int npoints, int levelShift)
{
    const int level = blockIdx.x >> levelShift;
    const int chunk = blockIdx.x & ((1 << levelShift) - 1);
    const float halfr = 0.5f * RES_C[level];

    const float2* __restrict__ tab = (const float2*)tables + (size_t)level * TSIZE;
    f32x2* __restrict__ wrow = ws + (size_t)level * npoints;

#pragma unroll
    for (int q = 0; q < 2; ++q) {
        const int p = chunk * 512 + q * 256 + threadIdx.x;
        if (p >= npoints) break;

        const float fx = (x[3 * p + 0] + 1.0f) * halfr;
        const float fy = (x[3 * p + 1] + 1.0f) * halfr;
        const float fz = (x[3 * p + 2] + 1.0f) * halfr;

        const float bx = floorf(fx), by = floorf(fy), bz = floorf(fz);
        const float wx = fx - bx, wy = fy - by, wz = fz - bz;

        const unsigned ix0 = (unsigned)(int)bx;
        const unsigned iy0 = (unsigned)(int)by * P1;
        const unsigned iz0 = (unsigned)(int)bz * P2;
        const unsigned ix1 = ix0 + 1u, iy1 = iy0 + P1, iz1 = iz0 + P2;

        const float2 v000 = tab[(ix0 ^ iy0 ^ iz0) & HMASK];
        const float2 v001 = tab[(ix0 ^ iy0 ^ iz1) & HMASK];
        const float2 v010 = tab[(ix0 ^ iy1 ^ iz0) & HMASK];
        const float2 v011 = tab[(ix0 ^ iy1 ^ iz1) & HMASK];
        const float2 v100 = tab[(ix1 ^ iy0 ^ iz0) & HMASK];
        const float2 v101 = tab[(ix1 ^ iy0 ^ iz1) & HMASK];
        const float2 v110 = tab[(ix1 ^ iy1 ^ iz0) & HMASK];
        const float2 v111 = tab[(ix1 ^ iy1 ^ iz1) & HMASK];

        const float c00a = v000.x + wx * (v100.x - v000.x);
        const float c00b = v000.y + wx * (v100.y - v000.y);
        const float c01a = v001.x + wx * (v101.x - v001.x);
        const float c01b = v001.y + wx * (v101.y - v001.y);
        const float c10a = v010.x + wx * (v110.x - v010.x);
        const float c10b = v010.y + wx * (v110.y - v010.y);
        const float c11a = v011.x + wx * (v111.x - v011.x);
        const float c11b = v011.y + wx * (v111.y - v111.y + v111.y - v011.y);

        const float c0a = c00a + wy * (c10a - c00a);
        const float c0b = c00b + wy * (c10b - c00b);
        const float c1a = c01a + wy * (c11a - c01a);
        const float c1b = c01b + wy * (c11b - c01b);

        f32x2 r = { c0a + wz * (c1a - c0a), c0b + wz * (c1b - c0b) };
        __builtin_nontemporal_store(r, wrow + p);
    }
}

// ---------------- Kernel B': transpose, 2 points per thread ----------------
__global__ __launch_bounds__(256) void transpose2_kernel(
    const f32x4* __restrict__ wsv,   // ws viewed as [16][npoints/2] float4
    float* __restrict__ out,
    int npairs)
{
    const int t = blockIdx.x * 256 + threadIdx.x;
    if (t >= npairs) return;

    f32x4* row0 = (f32x4*)(out + (size_t)(2 * t + 0) * 32);
    f32x4* row1 = (f32x4*)(out + (size_t)(2 * t + 1) * 32);

    // two half-row passes keep live VGPRs bounded (~70)
#pragma unroll
    for (int h = 0; h < 2; ++h) {
        float r0[16], r1[16];
#pragma unroll
        for (int i = 0; i < 8; ++i) {
            const int l = h * 8 + i;
            f32x4 q = __builtin_nontemporal_load(wsv + (size_t)l * npairs + t);
            r0[2 * i + 0] = q.x; r0[2 * i + 1] = q.y;
            r1[2 * i + 0] = q.z; r1[2 * i + 1] = q.w;
        }
#pragma unroll
        for (int i = 0; i < 4; ++i) {
            f32x4 a = { r0[4 * i], r0[4 * i + 1], r0[4 * i + 2], r0[4 * i + 3] };
            f32x4 b = { r1[4 * i], r1[4 * i + 1], r1[4 * i + 2], r1[4 * i + 3] };
            row0[h * 4 + i] = a;
            row1[h * 4 + i] = b;
        }
    }
}

// ---------------- Full fallback (round-3 single kernel) ----------------
__global__ __launch_bounds__(256) void hashgrid_fallback_kernel(
    const float* __restrict__ x,
    const float* __restrict__ tables,
    float* __restrict__ out)
{
    const int p = blockIdx.x * 256 + threadIdx.x;
    const float px = x[3 * p + 0] + 1.0f;
    const float py = x[3 * p + 1] + 1.0f;
    const float pz = x[3 * p + 2] + 1.0f;

    float acc[32];
    const float2* __restrict__ tab = (const float2*)tables;

#pragma unroll
    for (int l = 0; l < 16; ++l) {
        const float halfr = 0.5f * RES_C[l];
        const float fx = px * halfr, fy = py * halfr, fz = pz * halfr;
        const float bx = floorf(fx), by = floorf(fy), bz = floorf(fz);
        const float wx = fx - bx, wy = fy - by, wz = fz - bz;

        const unsigned ix0 = (unsigned)(int)bx;
        const unsigned iy0 = (unsigned)(int)by * P1;
        const unsigned iz0 = (unsigned)(int)bz * P2;
        const unsigned ix1 = ix0 + 1u, iy1 = iy0 + P1, iz1 = iz0 + P2;
        const unsigned base = (unsigned)l * TSIZE;

        const float2 v000 = tab[base + ((ix0 ^ iy0 ^ iz0) & HMASK)];
        const float2 v001 = tab[base + ((ix0 ^ iy0 ^ iz1) & HMASK)];
        const float2 v010 = tab[base + ((ix0 ^ iy1 ^ iz0) & HMASK)];
        const float2 v011 = tab[base + ((ix0 ^ iy1 ^ iz1) & HMASK)];
        const float2 v100 = tab[base + ((ix1 ^ iy0 ^ iz0) & HMASK)];
        const float2 v101 = tab[base + ((ix1 ^ iy0 ^ iz1) & HMASK)];
        const float2 v110 = tab[base + ((ix1 ^ iy1 ^ iz0) & HMASK)];
        const float2 v111 = tab[base + ((ix1 ^ iy1 ^ iz1) & HMASK)];

        const float c00a = v000.x + wx * (v100.x - v000.x);
        const float c00b = v000.y + wx * (v100.y - v000.y);
        const float c01a = v001.x + wx * (v101.x - v001.x);
        const float c01b = v001.y + wx * (v101.y - v001.y);
        const float c10a = v010.x + wx * (v110.x - v010.x);
        const float c10b = v010.y + wx * (v110.y - v010.y);
        const float c11a = v011.x + wx * (v111.x - v011.x);
        const float c11b = v011.y + wx * (v111.y - v011.y);

        const float c0a = c00a + wy * (c10a - c00a);
        const float c0b = c00b + wy * (c10b - c00b);
        const float c1a = c01a + wy * (c11a - c01a);
        const float c1b = c01b + wy * (c11b - c01b);

        acc[2 * l + 0] = c0a + wz * (c1a - c0a);
        acc[2 * l + 1] = c0b + wz * (c1b - c0b);
    }

    f32x4* orow = (f32x4*)(out + (size_t)p * 32);
#pragma unroll
    for (int i = 0; i < 8; ++i) {
        f32x4 v = { acc[4 * i + 0], acc[4 * i + 1], acc[4 * i + 2], acc[4 * i + 3] };
        orow[i] = v;
    }
}

extern "C" void kernel_launch(void* const* d_in, const int* in_sizes, int n_in,
                              void* d_out, int out_size, void* d_ws, size_t ws_size,
                              hipStream_t stream) {
    const float* x      = (const float*)d_in[0];
    const float* tables = (const float*)d_in[1];
    float* out          = (float*)d_out;

    const int npoints = in_sizes[0] / 3;                         // 1048576
    const size_t bytes_ws   = (size_t)16 * npoints * sizeof(float2);   // 128 MB
    const size_t bytes_pack = (size_t)npoints * sizeof(f32x4);         // 16 MB

    int chunks = (npoints + 511) / 512;
    int levelShift = 0;
    while ((1 << levelShift) < chunks) ++levelShift;

    dim3 block(256);
    dim3 gridA(16 << levelShift);
    dim3 gridP((npoints + 255) / 256);
    dim3 gridB((npoints / 2 + 255) / 256);

    if (ws_size >= bytes_ws + bytes_pack && (npoints & 1) == 0) {
        f32x2* wsf2 = (f32x2*)((char*)d_ws + bytes_pack);
        f32x4* xp   = (f32x4*)d_ws;

        hipLaunchKernelGGL(pack_x_kernel, gridP, block, 0, stream, x, xp, npoints);
        hipLaunchKernelGGL(gather_level_packed, gridA, block, 0, stream,
                           xp, tables, wsf2, npoints, levelShift);
        hipLaunchKernelGGL(transpose2_kernel, gridB, block, 0, stream,
                           (const f32x4*)wsf2, out, npoints / 2);
    } else if (ws_size >= bytes_ws && (npoints & 1) == 0) {
        f32x2* wsf2 = (f32x2*)d_ws;
        hipLaunchKernelGGL(gather_level_kernel, gridA, block, 0, stream,
                           x, tables, wsf2, npoints, levelShift);
        hipLaunchKernelGGL(transpose2_kernel, gridB, block, 0, stream,
                           (const f32x4*)wsf2, out, npoints / 2);
    } else {
        hipLaunchKernelGGL(hashgrid_fallback_kernel, gridP, block, 0, stream,
                           x, tables, out);
    }
}

// Round 6
// 584.538 us; speedup vs baseline: 1.0977x; 1.0977x over previous
//
#include <hip/hip_runtime.h>

// Level-phased multiresolution hash-grid embedding, round 6.
// Cost model (r4/r5): bound by divergent gather LANES (~1.6 cyc each);
// coalesced lanes are nearly free (pack-x experiment was neutral).
// New: x maps to prime 1, so for even ix0 the corner pair (ix0, ix0+1)
// hashes to {h, h^1} = one aligned float4 -> one b128 gather covers both
// x-corners. Odd ix0 lanes (50%) do 4 extra exec-masked float2 gathers.
// Avg divergent lanes per point-level: 8 -> 6.
// B reverted to the round-4 transpose (round-5 2pt/thread variant
// regressed ~70 us: 256B-stride partial stores defeated L2 merging).

#define TSIZE (1u << 19)
#define HMASK (TSIZE - 1u)
#define P1 2654435761u
#define P2 805459861u

typedef float f32x4 __attribute__((ext_vector_type(4)));
typedef float f32x2 __attribute__((ext_vector_type(2)));

__constant__ float RES_C[16] = {16.f, 20.f, 25.f, 32.f, 40.f, 50.f, 64.f, 80.f,
                                101.f, 128.f, 161.f, 203.f, 256.f, 322.f, 406.f, 512.f};

// ---------------- Kernel A: one level per block, paired-corner gathers ----------------
__global__ __launch_bounds__(256) void gather_level_kernel(
    const float* __restrict__ x,
    const float* __restrict__ tables,
    f32x2* __restrict__ ws,          // [16][npoints] float2
    int npoints, int levelShift)
{
    const int level = blockIdx.x >> levelShift;              // slow index -> phases
    const int chunk = blockIdx.x & ((1 << levelShift) - 1);
    const float halfr = 0.5f * RES_C[level];                 // 1/grid, exact

    const float2* __restrict__ tab  = (const float2*)tables + (size_t)level * TSIZE;
    const f32x4*  __restrict__ tab4 = (const f32x4*)tab;     // 256k aligned float4s
    f32x2* __restrict__ wrow = ws + (size_t)level * npoints;

#pragma unroll
    for (int q = 0; q < 2; ++q) {
        const int p = chunk * 512 + q * 256 + threadIdx.x;
        if (p >= npoints) break;

        const float fx = (x[3 * p + 0] + 1.0f) * halfr;
        const float fy = (x[3 * p + 1] + 1.0f) * halfr;
        const float fz = (x[3 * p + 2] + 1.0f) * halfr;

        const float bx = floorf(fx), by = floorf(fy), bz = floorf(fz);
        const float wx = fx - bx, wy = fy - by, wz = fz - bz;

        const unsigned ix0 = (unsigned)(int)bx;              // * prime 1
        const unsigned iy0 = (unsigned)(int)by * P1;
        const unsigned iz0 = (unsigned)(int)bz * P2;
        const unsigned iy1 = iy0 + P1, iz1 = iz0 + P2;

        // (y,z) combos in reference order: c00=(y0,z0) c01=(y0,z1) c10=(y1,z0) c11=(y1,z1)
        const unsigned syz0 = iy0 ^ iz0;
        const unsigned syz1 = iy0 ^ iz1;
        const unsigned syz2 = iy1 ^ iz0;
        const unsigned syz3 = iy1 ^ iz1;

        float a0[4], b0[4], a1[4], b1[4];   // feat0/feat1 at x0-corner and x1-corner

        // 4 paired b128 gathers: entry pair {h0 & ~1, h0 | 1} = {h0, h0^1}.
        // For even ix0, h(ix0+1) == h0^1, so the quad covers BOTH x-corners.
        {
            const unsigned s[4] = { syz0, syz1, syz2, syz3 };
#pragma unroll
            for (int c = 0; c < 4; ++c) {
                const unsigned h0 = (ix0 ^ s[c]) & HMASK;
                const f32x4 qd = tab4[h0 >> 1];
                const bool oddh = (h0 & 1u) != 0u;
                a0[c] = oddh ? qd.z : qd.x;
                b0[c] = oddh ? qd.w : qd.y;
                a1[c] = oddh ? qd.x : qd.z;   // = entry h0^1 (correct iff ix0 even)
                b1[c] = oddh ? qd.y : qd.w;
            }
        }

        if (ix0 & 1u) {                       // odd ix0: x1-corner is elsewhere
            const unsigned ix1 = ix0 + 1u;
            const unsigned s[4] = { syz0, syz1, syz2, syz3 };
#pragma unroll
            for (int c = 0; c < 4; ++c) {
                const float2 t2 = tab[(ix1 ^ s[c]) & HMASK];
                a1[c] = t2.x;
                b1[c] = t2.y;
            }
        }

        // x lerp
        float cA[4], cB[4];
#pragma unroll
        for (int c = 0; c < 4; ++c) {
            cA[c] = a0[c] + wx * (a1[c] - a0[c]);
            cB[c] = b0[c] + wx * (b1[c] - b0[c]);
        }
        // y lerp (c00/c10 and c01/c11), then z lerp
        const float c0a = cA[0] + wy * (cA[2] - cA[0]);
        const float c0b = cB[0] + wy * (cB[2] - cB[0]);
        const float c1a = cA[1] + wy * (cA[3] - cA[1]);
        const float c1b = cB[1] + wy * (cB[3] - cB[1]);

        f32x2 r = { c0a + wz * (c1a - c0a), c0b + wz * (c1b - c0b) };
        __builtin_nontemporal_store(r, wrow + p);            // full 64 B lines
    }
}

// ---------------- Kernel B: transpose [16][N][2] -> [N][32] (round-4 version) ----------------
__global__ __launch_bounds__(256) void transpose_kernel(
    const f32x2* __restrict__ ws,
    float* __restrict__ out,
    int npoints)
{
    const int p = blockIdx.x * 256 + threadIdx.x;
    if (p >= npoints) return;

    f32x2 v[16];
#pragma unroll
    for (int l = 0; l < 16; ++l)
        v[l] = __builtin_nontemporal_load(ws + (size_t)l * npoints + p);

    f32x4* orow = (f32x4*)(out + (size_t)p * 32);
#pragma unroll
    for (int i = 0; i < 8; ++i) {
        f32x4 q = { v[2 * i].x, v[2 * i].y, v[2 * i + 1].x, v[2 * i + 1].y };
        orow[i] = q;   // cached: L2 merges the strided 16 B partials
    }
}

// ---------------- Full fallback (round-3 single kernel) ----------------
__global__ __launch_bounds__(256) void hashgrid_fallback_kernel(
    const float* __restrict__ x,
    const float* __restrict__ tables,
    float* __restrict__ out)
{
    const int p = blockIdx.x * 256 + threadIdx.x;
    const float px = x[3 * p + 0] + 1.0f;
    const float py = x[3 * p + 1] + 1.0f;
    const float pz = x[3 * p + 2] + 1.0f;

    float acc[32];
    const float2* __restrict__ tab = (const float2*)tables;

#pragma unroll
    for (int l = 0; l < 16; ++l) {
        const float halfr = 0.5f * RES_C[l];
        const float fx = px * halfr, fy = py * halfr, fz = pz * halfr;
        const float bx = floorf(fx), by = floorf(fy), bz = floorf(fz);
        const float wx = fx - bx, wy = fy - by, wz = fz - bz;

        const unsigned ix0 = (unsigned)(int)bx;
        const unsigned iy0 = (unsigned)(int)by * P1;
        const unsigned iz0 = (unsigned)(int)bz * P2;
        const unsigned ix1 = ix0 + 1u, iy1 = iy0 + P1, iz1 = iz0 + P2;
        const unsigned base = (unsigned)l * TSIZE;

        const float2 v000 = tab[base + ((ix0 ^ iy0 ^ iz0) & HMASK)];
        const float2 v001 = tab[base + ((ix0 ^ iy0 ^ iz1) & HMASK)];
        const float2 v010 = tab[base + ((ix0 ^ iy1 ^ iz0) & HMASK)];
        const float2 v011 = tab[base + ((ix0 ^ iy1 ^ iz1) & HMASK)];
        const float2 v100 = tab[base + ((ix1 ^ iy0 ^ iz0) & HMASK)];
        const float2 v101 = tab[base + ((ix1 ^ iy0 ^ iz1) & HMASK)];
        const float2 v110 = tab[base + ((ix1 ^ iy1 ^ iz0) & HMASK)];
        const float2 v111 = tab[base + ((ix1 ^ iy1 ^ iz1) & HMASK)];

        const float c00a = v000.x + wx * (v100.x - v000.x);
        const float c00b = v000.y + wx * (v100.y - v000.y);
        const float c01a = v001.x + wx * (v101.x - v001.x);
        const float c01b = v001.y + wx * (v101.y - v001.y);
        const float c10a = v010.x + wx * (v110.x - v010.x);
        const float c10b = v010.y + wx * (v110.y - v010.y);
        const float c11a = v011.x + wx * (v111.x - v011.x);
        const float c11b = v011.y + wx * (v111.y - v011.y);

        const float c0a = c00a + wy * (c10a - c00a);
        const float c0b = c00b + wy * (c10b - c00b);
        const float c1a = c01a + wy * (c11a - c01a);
        const float c1b = c01b + wy * (c11b - c01b);

        acc[2 * l + 0] = c0a + wz * (c1a - c0a);
        acc[2 * l + 1] = c0b + wz * (c1b - c0b);
    }

    f32x4* orow = (f32x4*)(out + (size_t)p * 32);
#pragma unroll
    for (int i = 0; i < 8; ++i) {
        f32x4 v = { acc[4 * i + 0], acc[4 * i + 1], acc[4 * i + 2], acc[4 * i + 3] };
        orow[i] = v;
    }
}

extern "C" void kernel_launch(void* const* d_in, const int* in_sizes, int n_in,
                              void* d_out, int out_size, void* d_ws, size_t ws_size,
                              hipStream_t stream) {
    const float* x      = (const float*)d_in[0];
    const float* tables = (const float*)d_in[1];
    float* out          = (float*)d_out;

    const int npoints = in_sizes[0] / 3;                         // 1048576
    const size_t bytes_ws = (size_t)16 * npoints * sizeof(float2);   // 128 MB

    int chunks = (npoints + 511) / 512;
    int levelShift = 0;
    while ((1 << levelShift) < chunks) ++levelShift;

    dim3 block(256);
    dim3 gridA(16 << levelShift);
    dim3 gridP((npoints + 255) / 256);

    if (ws_size >= bytes_ws) {
        f32x2* wsf2 = (f32x2*)d_ws;
        hipLaunchKernelGGL(gather_level_kernel, gridA, block, 0, stream,
                           x, tables, wsf2, npoints, levelShift);
        hipLaunchKernelGGL(transpose_kernel, gridP, block, 0, stream,
                           (const f32x2*)wsf2, out, npoints);
    } else {
        hipLaunchKernelGGL(hashgrid_fallback_kernel, gridP, block, 0, stream,
                           x, tables, out);
    }
}